// Round 10
// baseline (247.073 us; speedup 1.0000x reference)
//
#include <hip/hip_runtime.h>
#include <hip/hip_bf16.h>
#include <cstdint>

#define D_ 1024
#define H_ 16
#define DH_ 64
#define FF_ 4096
#define B_ 2
#define S_ 2048
#define MR_ (B_ * S_)   // 4096 rows

typedef __bf16 bf16x8 __attribute__((ext_vector_type(8)));
typedef __bf16 bf16x4 __attribute__((ext_vector_type(4)));
typedef float f32x4 __attribute__((ext_vector_type(4)));
typedef float f32x16 __attribute__((ext_vector_type(16)));

// ---- async global->LDS, 16B per lane (linear dest in lane order) ----
__device__ __forceinline__ void g2lds16(const void* g, void* l) {
  __builtin_amdgcn_global_load_lds(
      (__attribute__((address_space(1))) void*)(uintptr_t)g,
      (__attribute__((address_space(3))) void*)(uint32_t)(uintptr_t)l,
      16, 0, 0);
}

// pack two f32 -> one u32 holding 2 bf16 (lo, hi)
__device__ __forceinline__ unsigned pkbf16(float lo, float hi) {
  unsigned r;
  asm("v_cvt_pk_bf16_f32 %0, %1, %2" : "=v"(r) : "v"(lo), "v"(hi));
  return r;
}

__device__ __forceinline__ float max3f(float a, float b, float c) {
  float d;
  asm("v_max3_f32 %0, %1, %2, %3" : "=v"(d) : "v"(a), "v"(b), "v"(c));
  return d;
}

__device__ __forceinline__ float rmax16(const f32x16& v) {
  float t0 = max3f(v[0], v[1], v[2]);
  float t1 = max3f(v[3], v[4], v[5]);
  float t2 = max3f(v[6], v[7], v[8]);
  float t3 = max3f(v[9], v[10], v[11]);
  float t4 = max3f(v[12], v[13], v[14]);
  return fmaxf(max3f(t0, t1, t2), max3f(t3, t4, v[15]));
}

// =====================  weight transpose + fp32->bf16  =====================
__global__ __launch_bounds__(256) void transpose_cvt(
    const float* __restrict__ W, __hip_bfloat16* __restrict__ Wt, int K, int N) {
  __shared__ float t[32][33];
  int bx = blockIdx.x * 32;  // n
  int by = blockIdx.y * 32;  // k
  int tx = threadIdx.x, ty = threadIdx.y;  // (32,8)
#pragma unroll
  for (int i = 0; i < 4; ++i)
    t[ty + 8 * i][tx] = W[(size_t)(by + ty + 8 * i) * N + bx + tx];
  __syncthreads();
#pragma unroll
  for (int i = 0; i < 4; ++i)
    Wt[(size_t)(bx + ty + 8 * i) * K + by + tx] = __float2bfloat16(t[tx][ty + 8 * i]);
}

// ==============  V slice transpose: qkv[b,s, 2D + h*64 + d] -> vT[b,h,d,s]  ==========
__global__ __launch_bounds__(256) void transpose_v(
    const __hip_bfloat16* __restrict__ qkv, __hip_bfloat16* __restrict__ vT) {
  __shared__ __hip_bfloat16 t[32][33];
  int bh = blockIdx.z, b = bh >> 4, h = bh & 15;
  int s0 = blockIdx.x * 32, d0 = blockIdx.y * 32;
  int tx = threadIdx.x, ty = threadIdx.y;
#pragma unroll
  for (int i = 0; i < 4; ++i)
    t[ty + 8 * i][tx] =
        qkv[(size_t)(b * S_ + s0 + ty + 8 * i) * (3 * D_) + 2 * D_ + h * DH_ + d0 + tx];
  __syncthreads();
#pragma unroll
  for (int i = 0; i < 4; ++i)
    vT[(size_t)(bh * DH_ + d0 + ty + 8 * i) * S_ + s0 + tx] = t[tx][ty + 8 * i];
}

// ==========================  LayerNorm (fp32 in, bf16 out)  ========================
__global__ __launch_bounds__(256) void ln_kernel(
    const float* __restrict__ x, const float* __restrict__ g,
    const float* __restrict__ b, __hip_bfloat16* __restrict__ out) {
  int row = blockIdx.x;
  const float4* xr = (const float4*)(x + (size_t)row * D_);
  float4 v = xr[threadIdx.x];
  float s = v.x + v.y + v.z + v.w;
  float ss = v.x * v.x + v.y * v.y + v.z * v.z + v.w * v.w;
#pragma unroll
  for (int m = 1; m < 64; m <<= 1) {
    s += __shfl_xor(s, m);
    ss += __shfl_xor(ss, m);
  }
  __shared__ float rs[4], rss[4];
  int wave = threadIdx.x >> 6, lane = threadIdx.x & 63;
  if (lane == 0) { rs[wave] = s; rss[wave] = ss; }
  __syncthreads();
  s = rs[0] + rs[1] + rs[2] + rs[3];
  ss = rss[0] + rss[1] + rss[2] + rss[3];
  float mean = s * (1.0f / D_);
  float var = ss * (1.0f / D_) - mean * mean;
  float inv = rsqrtf(var + 1e-5f);
  int c = threadIdx.x * 4;
  float4 gv = ((const float4*)g)[threadIdx.x];
  float4 bv = ((const float4*)b)[threadIdx.x];
  __hip_bfloat16* o = out + (size_t)row * D_ + c;
  o[0] = __float2bfloat16((v.x - mean) * inv * gv.x + bv.x);
  o[1] = __float2bfloat16((v.y - mean) * inv * gv.y + bv.y);
  o[2] = __float2bfloat16((v.z - mean) * inv * gv.z + bv.z);
  o[3] = __float2bfloat16((v.w - mean) * inv * gv.w + bv.w);
}

// ============  GEMM3: C[M,N] = A[M,K]*Bt[N,K]^T + bias (+epilogue)  =================
// BN=128 fixed; BM/wave-grid templated. 8 waves (WM x WN), per-wave (BM/WM)x(BN/WN).
// 3-buffer LDS ring: stage K-tile j+2 while computing j -> counted vmcnt(loads/tile).
// RACE GUARD (rule #18/#21): s_waitcnt lgkmcnt(0) + sched_barrier(0) before each
// barrier (hipcc can sink register-only MFMAs past inline-asm fences otherwise).
// EPI 0: bf16 +bias;  1: f32 +bias+resid;  2: bf16 +bias+gelu.
template <int EPI, int BM, int WM, int WN>
__global__ __launch_bounds__(512) void gemm3(
    const __hip_bfloat16* __restrict__ A, const __hip_bfloat16* __restrict__ Bt,
    const float* __restrict__ bias, const float* __restrict__ resid,
    void* __restrict__ outp, int M, int N, int K) {
  constexpr int BN = 128;
  constexpr int MF = BM / (WM * 16);
  constexpr int NF = BN / (WN * 16);
  constexpr int VMN = BM / 64 + 2;   // VMEM instrs per K-tile per thread
  __shared__ alignas(16) __hip_bfloat16 sA[3][BM * 64];
  __shared__ alignas(16) __hip_bfloat16 sB[3][BN * 64];
  const int tid = threadIdx.x;                 // 0..511
  const int lane = tid & 63, wave = tid >> 6;  // 8 waves
  const int l15 = lane & 15, l4 = lane >> 4;
  const int wr = wave / WN, wc = wave % WN;
  const int csw = (l15 & 7) << 3;              // read-side XOR swizzle

  // XCD-aware bijective block swizzle (all grids divisible by 8)
  const int gx = gridDim.x;
  int nwg = gx * gridDim.y;
  int flat = blockIdx.y * gx + blockIdx.x;
  int cpx = nwg >> 3;
  int swz = (flat & 7) * cpx + (flat >> 3);
  const int m0 = (swz / gx) * BM, n0 = (swz % gx) * BN;

  f32x4 z = {0.f, 0.f, 0.f, 0.f};
  f32x4 acc[MF][NF];
#pragma unroll
  for (int i = 0; i < MF; ++i)
#pragma unroll
    for (int j = 0; j < NF; ++j) acc[i][j] = z;

  auto stageA = [&](int bu, int kt) {   // BM/64 VMEM instr / thread
#pragma unroll
    for (int it = 0; it < BM / 64; ++it) {
      int idx = it * 512 + tid;
      int r = idx >> 3, c = (idx & 7) * 8;
      int cs = c ^ ((r & 7) << 3);
      g2lds16(A + (size_t)(m0 + r) * K + kt + cs, (void*)(&sA[bu][idx * 8]));
    }
  };
  auto stageB = [&](int bu, int kt) {   // 2 VMEM instr / thread
#pragma unroll
    for (int it = 0; it < 2; ++it) {
      int idx = it * 512 + tid;
      int r = idx >> 3, c = (idx & 7) * 8;
      int cs = c ^ ((r & 7) << 3);
      g2lds16(Bt + (size_t)(n0 + r) * K + kt + cs, (void*)(&sB[bu][idx * 8]));
    }
  };

  const int nk = K / 64;
  // prologue: stage tiles 0 and 1 -> wait tile 0 (vmcnt = one tile's loads)
  stageA(0, 0);
  stageB(0, 0);
  stageA(1, 64);
  stageB(1, 64);
  if constexpr (VMN == 6)
    asm volatile("s_waitcnt vmcnt(6)" ::: "memory");
  else
    asm volatile("s_waitcnt vmcnt(4)" ::: "memory");
  __builtin_amdgcn_s_barrier();

  int bu = 0, bu2 = 2;  // compute buf, prefetch buf (=(j+2)%3)
  for (int j = 0; j < nk; ++j) {
    const bool pf = (j + 2) < nk;
    if (pf) stageA(bu2, (j + 2) * 64);   // issue early

    __builtin_amdgcn_s_setprio(1);
#pragma unroll
    for (int kk = 0; kk < 2; ++kk) {
      bf16x8 bfr[NF];
      int col = (kk * 32 + l4 * 8) ^ csw;
#pragma unroll
      for (int nf = 0; nf < NF; ++nf)
        bfr[nf] = *(const bf16x8*)(&sB[bu][(wc * NF * 16 + nf * 16 + l15) * 64 + col]);
#pragma unroll
      for (int mf = 0; mf < MF; ++mf) {
        bf16x8 af = *(const bf16x8*)(&sA[bu][(wr * MF * 16 + mf * 16 + l15) * 64 + col]);
#pragma unroll
        for (int nf = 0; nf < NF; ++nf)
          acc[mf][nf] =
              __builtin_amdgcn_mfma_f32_16x16x32_bf16(af, bfr[nf], acc[mf][nf], 0, 0, 0);
      }
    }
    __builtin_amdgcn_s_setprio(0);

    if (pf) stageB(bu2, (j + 2) * 64);

    // RACE GUARD: this wave's ds_reads must have landed before it signals the
    // barrier (next iteration's load_lds overwrites the buffer they target).
    asm volatile("s_waitcnt lgkmcnt(0)" ::: "memory");
    __builtin_amdgcn_sched_barrier(0);

    if (pf) {
      if constexpr (VMN == 6)
        asm volatile("s_waitcnt vmcnt(6)" ::: "memory");  // drain tile j+1 only
      else
        asm volatile("s_waitcnt vmcnt(4)" ::: "memory");
    } else {
      asm volatile("s_waitcnt vmcnt(0)" ::: "memory");    // tail
    }
    __builtin_amdgcn_s_barrier();
    asm volatile("" ::: "memory");
    bu = (bu == 2) ? 0 : bu + 1;
    bu2 = (bu2 == 2) ? 0 : bu2 + 1;
  }

  // epilogue
#pragma unroll
  for (int mf = 0; mf < MF; ++mf) {
#pragma unroll
    for (int nf = 0; nf < NF; ++nf) {
      int col = n0 + wc * NF * 16 + nf * 16 + l15;
      float bv = bias[col];
#pragma unroll
      for (int j = 0; j < 4; ++j) {
        int row = m0 + wr * MF * 16 + mf * 16 + l4 * 4 + j;
        size_t o = (size_t)row * N + col;
        float v = acc[mf][nf][j] + bv;
        if (EPI == 0) {
          ((__hip_bfloat16*)outp)[o] = __float2bfloat16(v);
        } else if (EPI == 1) {
          ((float*)outp)[o] = v + resid[o];
        } else {
          float a = 0.7978845608028654f * (v + 0.044715f * v * v * v);
          a = fminf(fmaxf(a, -15.f), 15.f);
          float e = __expf(2.f * a);
          float th = (e - 1.f) / (e + 1.f);
          ((__hip_bfloat16*)outp)[o] = __float2bfloat16(0.5f * v * (1.f + th));
        }
      }
    }
  }
}

// ===============  Flash attention: 32x32 MFMA, in-register softmax  ================
// 2 waves/block (128 thr), QBLK=64 -> grid (S/64, B*H) = 1024 blocks = 4 blocks/CU
// = 4 waves/SIMD (occupancy fix: VGPR=112 and LDS=33KB both allow 4; grid was the cap).
// Q pre-scaled by k2 = 0.125*log2(e) at load -> scores already in log2 units.
__global__ __launch_bounds__(128) void attn_kernel(
    const __hip_bfloat16* __restrict__ qkv, const __hip_bfloat16* __restrict__ vT,
    __hip_bfloat16* __restrict__ out) {
  __shared__ alignas(16) __hip_bfloat16 sK[2][64 * 64];   // [kv][dh], swizzled
  __shared__ alignas(16) __hip_bfloat16 sV[2][64 * 64];   // [dh][kv], swizzled
  __shared__ float sBr[2][32];                            // per-wave q-broadcast (rescale)
  const int tid = threadIdx.x, lane = tid & 63, wave = tid >> 6;  // 2 waves
  const int l31 = lane & 31, hi = lane >> 5;
  const int bh = blockIdx.y, b = bh >> 4, h = bh & 15;
  const int q0 = blockIdx.x * 64;
  const int rsw = (l31 & 7) << 3;
  const float k2 = 0.125f * 1.44269504f;

  // Q as B-operand, pre-scaled by k2 (scores come out of MFMA in log2 units)
  bf16x8 qf[4];
  {
    int qr = q0 + wave * 32 + l31;
    const size_t qbase = ((size_t)(b * S_ + qr)) * (3 * D_) + h * DH_;
#pragma unroll
    for (int ks = 0; ks < 4; ++ks) {
      bf16x8 q = *(const bf16x8*)(qkv + qbase + ks * 16 + hi * 8);
#pragma unroll
      for (int i = 0; i < 8; ++i) q[i] = (__bf16)((float)q[i] * k2);
      qf[ks] = q;
    }
  }

  bf16x8 onesb;
#pragma unroll
  for (int i = 0; i < 8; ++i) onesb[i] = (__bf16)1.0f;

  f32x16 acc0, acc1, accL;
#pragma unroll
  for (int r = 0; r < 16; ++r) { acc0[r] = 0.f; acc1[r] = 0.f; accL[r] = 0.f; }
  float mrun = -1e30f;

  const __hip_bfloat16* kg = qkv + (size_t)b * S_ * (3 * D_) + D_ + h * DH_;
  const __hip_bfloat16* vg = vT + (size_t)bh * DH_ * S_;

  auto stage = [&](int bu, int kv0) {
#pragma unroll
    for (int it = 0; it < 4; ++it) {
      int idx = it * 128 + tid;          // 0..511
      int r = idx >> 3;
      int c = (idx & 7) * 8;
      int cs = c ^ ((r & 7) << 3);
      g2lds16(kg + (size_t)(kv0 + r) * (3 * D_) + cs, (void*)(&sK[bu][idx * 8]));
      g2lds16(vg + (size_t)r * S_ + kv0 + cs, (void*)(&sV[bu][idx * 8]));
    }
  };

  stage(0, 0);
  const int NT = S_ / 64;

  for (int t = 0; t < NT; ++t) {
    const int cur = t & 1;
    __syncthreads();
    if (t + 1 < NT) stage(cur ^ 1, (t + 1) * 64);

    f32x16 sf0, sf1;
#pragma unroll
    for (int r = 0; r < 16; ++r) { sf0[r] = 0.f; sf1[r] = 0.f; }
    __builtin_amdgcn_s_setprio(1);
#pragma unroll
    for (int ks = 0; ks < 4; ++ks) {
      int colsw = (ks * 16 + hi * 8) ^ rsw;
      bf16x8 kf0 = *(const bf16x8*)(&sK[cur][l31 * 64 + colsw]);
      bf16x8 kf1 = *(const bf16x8*)(&sK[cur][(32 + l31) * 64 + colsw]);
      sf0 = __builtin_amdgcn_mfma_f32_32x32x16_bf16(kf0, qf[ks], sf0, 0, 0, 0);
      sf1 = __builtin_amdgcn_mfma_f32_32x32x16_bf16(kf1, qf[ks], sf1, 0, 0, 0);
    }
    __builtin_amdgcn_s_setprio(0);

    float pm = fmaxf(rmax16(sf0), rmax16(sf1));   // already log2 units
    if (!__all(pm - mrun <= 8.0f)) {
      float mf = fmaxf(pm, __shfl_xor(pm, 32));
      float mn = fmaxf(mrun, mf);
      float corrl = exp2f(mrun - mn);
      mrun = mn;
      sBr[wave][l31] = corrl;
#pragma unroll
      for (int r = 0; r < 16; ++r) {
        float cr = sBr[wave][(r & 3) + 8 * (r >> 2) + 4 * hi];
        acc0[r] *= cr;
        acc1[r] *= cr;
        accL[r] *= cr;
      }
    }

    bf16x8 pa[4];
#pragma unroll
    for (int kb = 0; kb < 2; ++kb) {
      const f32x16 s16 = kb ? sf1 : sf0;
#pragma unroll
      for (int ksb = 0; ksb < 2; ++ksb) {
        float p0 = exp2f(s16[8 * ksb + 0] - mrun);
        float p1 = exp2f(s16[8 * ksb + 1] - mrun);
        float p2 = exp2f(s16[8 * ksb + 2] - mrun);
        float p3 = exp2f(s16[8 * ksb + 3] - mrun);
        float p4 = exp2f(s16[8 * ksb + 4] - mrun);
        float p5 = exp2f(s16[8 * ksb + 5] - mrun);
        float p6 = exp2f(s16[8 * ksb + 6] - mrun);
        float p7 = exp2f(s16[8 * ksb + 7] - mrun);
        unsigned wa = pkbf16(p0, p1), wb = pkbf16(p2, p3);
        unsigned wc = pkbf16(p4, p5), wd = pkbf16(p6, p7);
        auto r1 = __builtin_amdgcn_permlane32_swap(wa, wc, false, false);
        auto r2 = __builtin_amdgcn_permlane32_swap(wb, wd, false, false);
        union { unsigned u[4]; bf16x8 v; } w;
        w.u[0] = r1[0]; w.u[1] = r2[0]; w.u[2] = r1[1]; w.u[3] = r2[1];
        pa[kb * 2 + ksb] = w.v;
      }
    }

    __builtin_amdgcn_s_setprio(1);
#pragma unroll
    for (int ksg = 0; ksg < 4; ++ksg) {
      int colsw = (ksg * 16 + hi * 8) ^ rsw;
      bf16x8 vf0 = *(const bf16x8*)(&sV[cur][l31 * 64 + colsw]);
      bf16x8 vf1 = *(const bf16x8*)(&sV[cur][(32 + l31) * 64 + colsw]);
      acc0 = __builtin_amdgcn_mfma_f32_32x32x16_bf16(pa[ksg], vf0, acc0, 0, 0, 0);
      acc1 = __builtin_amdgcn_mfma_f32_32x32x16_bf16(pa[ksg], vf1, acc1, 0, 0, 0);
      accL = __builtin_amdgcn_mfma_f32_32x32x16_bf16(pa[ksg], onesb, accL, 0, 0, 0);
    }
    __builtin_amdgcn_s_setprio(0);
  }

#pragma unroll
  for (int r = 0; r < 16; ++r) {
    int qrow = (r & 3) + 8 * (r >> 2) + 4 * hi;
    float ir = 1.0f / accL[r];
    size_t obase = ((size_t)(b * S_ + q0 + wave * 32 + qrow)) * D_ + h * DH_ + l31;
    out[obase] = __float2bfloat16(acc0[r] * ir);
    out[obase + 32] = __float2bfloat16(acc1[r] * ir);
  }
}

// ====================================================================================
extern "C" void kernel_launch(void* const* d_in, const int* in_sizes, int n_in,
                              void* d_out, int out_size, void* d_ws, size_t ws_size,
                              hipStream_t stream) {
  const float* x = (const float*)d_in[0];
  const float* ln1_g = (const float*)d_in[1];
  const float* ln1_b = (const float*)d_in[2];
  const float* Wqkv = (const float*)d_in[3];
  const float* bqkv = (const float*)d_in[4];
  const float* Wo = (const float*)d_in[5];
  const float* bo = (const float*)d_in[6];
  const float* ln2_g = (const float*)d_in[7];
  const float* ln2_b = (const float*)d_in[8];
  const float* W1 = (const float*)d_in[9];
  const float* b1 = (const float*)d_in[10];
  const float* W2 = (const float*)d_in[11];
  const float* b2 = (const float*)d_in[12];
  float* out = (float*)d_out;

  char* ws = (char*)d_ws;
  size_t off = 0;
  auto alloc = [&](size_t bytes) {
    void* p = ws + off;
    off += (bytes + 255) & ~(size_t)255;
    return p;
  };
  __hip_bfloat16* WqkvT = (__hip_bfloat16*)alloc((size_t)3 * D_ * D_ * 2);
  __hip_bfloat16* WoT = (__hip_bfloat16*)alloc((size_t)D_ * D_ * 2);
  __hip_bfloat16* W1T = (__hip_bfloat16*)alloc((size_t)FF_ * D_ * 2);
  __hip_bfloat16* W2T = (__hip_bfloat16*)alloc((size_t)D_ * FF_ * 2);
  __hip_bfloat16* h = (__hip_bfloat16*)alloc((size_t)MR_ * D_ * 2);
  __hip_bfloat16* qkv = (__hip_bfloat16*)alloc((size_t)MR_ * FF_ * 2);  // shared w/ ff
  __hip_bfloat16* ff = qkv;
  __hip_bfloat16* vT = (__hip_bfloat16*)alloc((size_t)B_ * H_ * DH_ * S_ * 2);
  __hip_bfloat16* attn_out = (__hip_bfloat16*)alloc((size_t)MR_ * D_ * 2);

  dim3 tb(32, 8);
  // 1. weight prep
  transpose_cvt<<<dim3(3 * D_ / 32, D_ / 32), tb, 0, stream>>>(Wqkv, WqkvT, D_, 3 * D_);
  transpose_cvt<<<dim3(D_ / 32, D_ / 32), tb, 0, stream>>>(Wo, WoT, D_, D_);
  transpose_cvt<<<dim3(FF_ / 32, D_ / 32), tb, 0, stream>>>(W1, W1T, D_, FF_);
  transpose_cvt<<<dim3(D_ / 32, FF_ / 32), tb, 0, stream>>>(W2, W2T, FF_, D_);
  // 2. LN1
  ln_kernel<<<MR_, 256, 0, stream>>>(x, ln1_g, ln1_b, h);
  // 3. QKV gemm: 128x128 tile -> grid (24,32) = 768
  gemm3<0, 128, 2, 4><<<dim3(3 * D_ / 128, MR_ / 128), 512, 0, stream>>>(
      h, WqkvT, bqkv, nullptr, qkv, MR_, 3 * D_, D_);
  // 4. V transpose
  transpose_v<<<dim3(S_ / 32, DH_ / 32, B_ * H_), tb, 0, stream>>>(qkv, vT);
  // 5. attention: QBLK=64, 2 waves -> grid (32,32) = 1024 = 4 blocks/CU
  attn_kernel<<<dim3(S_ / 64, B_ * H_), 128, 0, stream>>>(qkv, vT, attn_out);
  // 6. Wo gemm + residual -> d_out (fp32): 128x128 -> grid (8,32) = 256
  gemm3<1, 128, 2, 4><<<dim3(D_ / 128, MR_ / 128), 512, 0, stream>>>(
      attn_out, WoT, bo, x, out, MR_, D_, D_);
  // 7. LN2 (reuse h)
  ln_kernel<<<MR_, 256, 0, stream>>>(out, ln2_g, ln2_b, h);
  // 8. W1 gemm + gelu: 256x128 -> grid (32,16) = 512
  gemm3<2, 256, 4, 2><<<dim3(FF_ / 128, MR_ / 256), 512, 0, stream>>>(
      h, W1T, b1, nullptr, ff, MR_, FF_, D_);
  // 9. W2 gemm + residual(d_out) -> d_out: 128x128 -> grid (8,32) = 256
  gemm3<1, 128, 2, 4><<<dim3(D_ / 128, MR_ / 128), 512, 0, stream>>>(
      ff, W2T, b2, out, out, MR_, D_, FF_);
}

// Round 11
// 234.696 us; speedup vs baseline: 1.0527x; 1.0527x over previous
//
#include <hip/hip_runtime.h>
#include <hip/hip_bf16.h>
#include <cstdint>

#define D_ 1024
#define H_ 16
#define DH_ 64
#define FF_ 4096
#define B_ 2
#define S_ 2048
#define MR_ (B_ * S_)   // 4096 rows

typedef __bf16 bf16x8 __attribute__((ext_vector_type(8)));
typedef __bf16 bf16x4 __attribute__((ext_vector_type(4)));
typedef float f32x4 __attribute__((ext_vector_type(4)));
typedef float f32x16 __attribute__((ext_vector_type(16)));

// ---- async global->LDS, 16B per lane (linear dest in lane order) ----
__device__ __forceinline__ void g2lds16(const void* g, void* l) {
  __builtin_amdgcn_global_load_lds(
      (__attribute__((address_space(1))) void*)(uintptr_t)g,
      (__attribute__((address_space(3))) void*)(uint32_t)(uintptr_t)l,
      16, 0, 0);
}

// pack two f32 -> one u32 holding 2 bf16 (lo, hi)
__device__ __forceinline__ unsigned pkbf16(float lo, float hi) {
  unsigned r;
  asm("v_cvt_pk_bf16_f32 %0, %1, %2" : "=v"(r) : "v"(lo), "v"(hi));
  return r;
}

__device__ __forceinline__ float max3f(float a, float b, float c) {
  float d;
  asm("v_max3_f32 %0, %1, %2, %3" : "=v"(d) : "v"(a), "v"(b), "v"(c));
  return d;
}

__device__ __forceinline__ float rmax16(const f32x16& v) {
  float t0 = max3f(v[0], v[1], v[2]);
  float t1 = max3f(v[3], v[4], v[5]);
  float t2 = max3f(v[6], v[7], v[8]);
  float t3 = max3f(v[9], v[10], v[11]);
  float t4 = max3f(v[12], v[13], v[14]);
  return fmaxf(max3f(t0, t1, t2), max3f(t3, t4, v[15]));
}

// =====================  weight transpose + fp32->bf16  =====================
__global__ __launch_bounds__(256) void transpose_cvt(
    const float* __restrict__ W, __hip_bfloat16* __restrict__ Wt, int K, int N) {
  __shared__ float t[32][33];
  int bx = blockIdx.x * 32;  // n
  int by = blockIdx.y * 32;  // k
  int tx = threadIdx.x, ty = threadIdx.y;  // (32,8)
#pragma unroll
  for (int i = 0; i < 4; ++i)
    t[ty + 8 * i][tx] = W[(size_t)(by + ty + 8 * i) * N + bx + tx];
  __syncthreads();
#pragma unroll
  for (int i = 0; i < 4; ++i)
    Wt[(size_t)(bx + ty + 8 * i) * K + by + tx] = __float2bfloat16(t[tx][ty + 8 * i]);
}

// ==============  V slice transpose: qkv[b,s, 2D + h*64 + d] -> vT[b,h,d,s]  ==========
__global__ __launch_bounds__(256) void transpose_v(
    const __hip_bfloat16* __restrict__ qkv, __hip_bfloat16* __restrict__ vT) {
  __shared__ __hip_bfloat16 t[32][33];
  int bh = blockIdx.z, b = bh >> 4, h = bh & 15;
  int s0 = blockIdx.x * 32, d0 = blockIdx.y * 32;
  int tx = threadIdx.x, ty = threadIdx.y;
#pragma unroll
  for (int i = 0; i < 4; ++i)
    t[ty + 8 * i][tx] =
        qkv[(size_t)(b * S_ + s0 + ty + 8 * i) * (3 * D_) + 2 * D_ + h * DH_ + d0 + tx];
  __syncthreads();
#pragma unroll
  for (int i = 0; i < 4; ++i)
    vT[(size_t)(bh * DH_ + d0 + ty + 8 * i) * S_ + s0 + tx] = t[tx][ty + 8 * i];
}

// ==========================  LayerNorm (fp32 in, bf16 out)  ========================
__global__ __launch_bounds__(256) void ln_kernel(
    const float* __restrict__ x, const float* __restrict__ g,
    const float* __restrict__ b, __hip_bfloat16* __restrict__ out) {
  int row = blockIdx.x;
  const float4* xr = (const float4*)(x + (size_t)row * D_);
  float4 v = xr[threadIdx.x];
  float s = v.x + v.y + v.z + v.w;
  float ss = v.x * v.x + v.y * v.y + v.z * v.z + v.w * v.w;
#pragma unroll
  for (int m = 1; m < 64; m <<= 1) {
    s += __shfl_xor(s, m);
    ss += __shfl_xor(ss, m);
  }
  __shared__ float rs[4], rss[4];
  int wave = threadIdx.x >> 6, lane = threadIdx.x & 63;
  if (lane == 0) { rs[wave] = s; rss[wave] = ss; }
  __syncthreads();
  s = rs[0] + rs[1] + rs[2] + rs[3];
  ss = rss[0] + rss[1] + rss[2] + rss[3];
  float mean = s * (1.0f / D_);
  float var = ss * (1.0f / D_) - mean * mean;
  float inv = rsqrtf(var + 1e-5f);
  int c = threadIdx.x * 4;
  float4 gv = ((const float4*)g)[threadIdx.x];
  float4 bv = ((const float4*)b)[threadIdx.x];
  __hip_bfloat16* o = out + (size_t)row * D_ + c;
  o[0] = __float2bfloat16((v.x - mean) * inv * gv.x + bv.x);
  o[1] = __float2bfloat16((v.y - mean) * inv * gv.y + bv.y);
  o[2] = __float2bfloat16((v.z - mean) * inv * gv.z + bv.z);
  o[3] = __float2bfloat16((v.w - mean) * inv * gv.w + bv.w);
}

// ============  GEMM3: C[M,N] = A[M,K]*Bt[N,K]^T + bias (+epilogue)  =================
// Uniform 128x128 tile, BK=64, 8 waves (WM=2 x WN=4), per-wave 64x32 (MF=4, NF=2).
// 2-buffer ring (64 KB -> 2 blocks/CU resident): stage(j+1) issued BEFORE compute(j)
// so loads fly under the MFMA phase; one barrier per iter; inter-block overlap covers
// the vmcnt(0) drain (T3-minimum + 2 blocks/CU, m248/m114 mechanism).
// RACE GUARD (rule #18): lgkmcnt(0)+sched_barrier(0) before signaling the barrier.
// XOR bank swizzle both-sides. XCD-aware bijective block swizzle (grids % 8 == 0).
// EPI 0: bf16 +bias;  1: f32 +bias+resid;  2: bf16 +bias+gelu.
template <int EPI>
__global__ __launch_bounds__(512) void gemm3(
    const __hip_bfloat16* __restrict__ A, const __hip_bfloat16* __restrict__ Bt,
    const float* __restrict__ bias, const float* __restrict__ resid,
    void* __restrict__ outp, int M, int N, int K) {
  constexpr int BM = 128, BN = 128, MF = 4, NF = 2, WN = 4;
  __shared__ alignas(16) __hip_bfloat16 sA[2][BM * 64];
  __shared__ alignas(16) __hip_bfloat16 sB[2][BN * 64];
  const int tid = threadIdx.x;                 // 0..511
  const int lane = tid & 63, wave = tid >> 6;  // 8 waves
  const int l15 = lane & 15, l4 = lane >> 4;
  const int wr = wave / WN, wc = wave % WN;
  const int csw = (l15 & 7) << 3;              // read-side XOR swizzle

  // XCD-aware bijective block swizzle (all grids divisible by 8)
  const int gx = gridDim.x;
  int nwg = gx * gridDim.y;
  int flat = blockIdx.y * gx + blockIdx.x;
  int cpx = nwg >> 3;
  int swz = (flat & 7) * cpx + (flat >> 3);
  const int m0 = (swz / gx) * BM, n0 = (swz % gx) * BN;

  f32x4 z = {0.f, 0.f, 0.f, 0.f};
  f32x4 acc[MF][NF];
#pragma unroll
  for (int i = 0; i < MF; ++i)
#pragma unroll
    for (int j = 0; j < NF; ++j) acc[i][j] = z;

  auto stage = [&](int bu, int kt) {   // 2+2 VMEM instr / thread
#pragma unroll
    for (int it = 0; it < 2; ++it) {
      int idx = it * 512 + tid;
      int r = idx >> 3, c = (idx & 7) * 8;
      int cs = c ^ ((r & 7) << 3);
      g2lds16(A + (size_t)(m0 + r) * K + kt + cs, (void*)(&sA[bu][idx * 8]));
      g2lds16(Bt + (size_t)(n0 + r) * K + kt + cs, (void*)(&sB[bu][idx * 8]));
    }
  };

  const int nk = K / 64;
  stage(0, 0);
  asm volatile("s_waitcnt vmcnt(0)" ::: "memory");
  __builtin_amdgcn_s_barrier();

  for (int j = 0; j < nk; ++j) {
    const int cur = j & 1;
    if (j + 1 < nk) stage(cur ^ 1, (j + 1) * 64);  // issue early; flies under MFMA

    __builtin_amdgcn_s_setprio(1);
#pragma unroll
    for (int kk = 0; kk < 2; ++kk) {
      bf16x8 bfr[NF];
      int col = (kk * 32 + l4 * 8) ^ csw;
#pragma unroll
      for (int nf = 0; nf < NF; ++nf)
        bfr[nf] = *(const bf16x8*)(&sB[cur][(wc * NF * 16 + nf * 16 + l15) * 64 + col]);
#pragma unroll
      for (int mf = 0; mf < MF; ++mf) {
        bf16x8 af = *(const bf16x8*)(&sA[cur][(wr * MF * 16 + mf * 16 + l15) * 64 + col]);
#pragma unroll
        for (int nf = 0; nf < NF; ++nf)
          acc[mf][nf] =
              __builtin_amdgcn_mfma_f32_16x16x32_bf16(af, bfr[nf], acc[mf][nf], 0, 0, 0);
      }
    }
    __builtin_amdgcn_s_setprio(0);

    // RACE GUARD: this wave's ds_reads of buf[cur] must land before the barrier
    // (next iteration stages into buf[cur]).
    asm volatile("s_waitcnt lgkmcnt(0)" ::: "memory");
    __builtin_amdgcn_sched_barrier(0);
    // prefetch landed (it flew during compute); other resident block hides this
    asm volatile("s_waitcnt vmcnt(0)" ::: "memory");
    __builtin_amdgcn_s_barrier();
    asm volatile("" ::: "memory");
  }

  // epilogue
#pragma unroll
  for (int mf = 0; mf < MF; ++mf) {
#pragma unroll
    for (int nf = 0; nf < NF; ++nf) {
      int col = n0 + wc * NF * 16 + nf * 16 + l15;
      float bv = bias[col];
#pragma unroll
      for (int j = 0; j < 4; ++j) {
        int row = m0 + wr * MF * 16 + mf * 16 + l4 * 4 + j;
        size_t o = (size_t)row * N + col;
        float v = acc[mf][nf][j] + bv;
        if (EPI == 0) {
          ((__hip_bfloat16*)outp)[o] = __float2bfloat16(v);
        } else if (EPI == 1) {
          ((float*)outp)[o] = v + resid[o];
        } else {
          float a = 0.7978845608028654f * (v + 0.044715f * v * v * v);
          a = fminf(fmaxf(a, -15.f), 15.f);
          float e = __expf(2.f * a);
          float th = (e - 1.f) / (e + 1.f);
          ((__hip_bfloat16*)outp)[o] = __float2bfloat16(0.5f * v * (1.f + th));
        }
      }
    }
  }
}

// ===============  Flash attention: 32x32 MFMA, in-register softmax  ================
// R9 config (confirmed fastest): 4 waves/block, QBLK=128, grid (S/128, B*H) = 512.
// Q pre-scaled by k2 = 0.125*log2(e) at load -> scores already in log2 units.
__global__ __launch_bounds__(256) void attn_kernel(
    const __hip_bfloat16* __restrict__ qkv, const __hip_bfloat16* __restrict__ vT,
    __hip_bfloat16* __restrict__ out) {
  __shared__ alignas(16) __hip_bfloat16 sK[2][64 * 64];   // [kv][dh], swizzled
  __shared__ alignas(16) __hip_bfloat16 sV[2][64 * 64];   // [dh][kv], swizzled
  __shared__ float sBr[4][32];                            // per-wave q-broadcast (rescale)
  const int tid = threadIdx.x, lane = tid & 63, wave = tid >> 6;
  const int l31 = lane & 31, hi = lane >> 5;
  const int bh = blockIdx.y, b = bh >> 4, h = bh & 15;
  const int q0 = blockIdx.x * 128;
  const int rsw = (l31 & 7) << 3;
  const float k2 = 0.125f * 1.44269504f;

  // Q as B-operand, pre-scaled by k2 (scores come out of MFMA in log2 units)
  bf16x8 qf[4];
  {
    int qr = q0 + wave * 32 + l31;
    const size_t qbase = ((size_t)(b * S_ + qr)) * (3 * D_) + h * DH_;
#pragma unroll
    for (int ks = 0; ks < 4; ++ks) {
      bf16x8 q = *(const bf16x8*)(qkv + qbase + ks * 16 + hi * 8);
#pragma unroll
      for (int i = 0; i < 8; ++i) q[i] = (__bf16)((float)q[i] * k2);
      qf[ks] = q;
    }
  }

  bf16x8 onesb;
#pragma unroll
  for (int i = 0; i < 8; ++i) onesb[i] = (__bf16)1.0f;

  f32x16 acc0, acc1, accL;
#pragma unroll
  for (int r = 0; r < 16; ++r) { acc0[r] = 0.f; acc1[r] = 0.f; accL[r] = 0.f; }
  float mrun = -1e30f;

  const __hip_bfloat16* kg = qkv + (size_t)b * S_ * (3 * D_) + D_ + h * DH_;
  const __hip_bfloat16* vg = vT + (size_t)bh * DH_ * S_;

  auto stage = [&](int bu, int kv0) {
#pragma unroll
    for (int it = 0; it < 2; ++it) {
      int idx = it * 256 + tid;
      int r = idx >> 3;
      int c = (idx & 7) * 8;
      int cs = c ^ ((r & 7) << 3);
      g2lds16(kg + (size_t)(kv0 + r) * (3 * D_) + cs, (void*)(&sK[bu][idx * 8]));
      g2lds16(vg + (size_t)r * S_ + kv0 + cs, (void*)(&sV[bu][idx * 8]));
    }
  };

  stage(0, 0);
  const int NT = S_ / 64;

  for (int t = 0; t < NT; ++t) {
    const int cur = t & 1;
    __syncthreads();
    if (t + 1 < NT) stage(cur ^ 1, (t + 1) * 64);

    f32x16 sf0, sf1;
#pragma unroll
    for (int r = 0; r < 16; ++r) { sf0[r] = 0.f; sf1[r] = 0.f; }
    __builtin_amdgcn_s_setprio(1);
#pragma unroll
    for (int ks = 0; ks < 4; ++ks) {
      int colsw = (ks * 16 + hi * 8) ^ rsw;
      bf16x8 kf0 = *(const bf16x8*)(&sK[cur][l31 * 64 + colsw]);
      bf16x8 kf1 = *(const bf16x8*)(&sK[cur][(32 + l31) * 64 + colsw]);
      sf0 = __builtin_amdgcn_mfma_f32_32x32x16_bf16(kf0, qf[ks], sf0, 0, 0, 0);
      sf1 = __builtin_amdgcn_mfma_f32_32x32x16_bf16(kf1, qf[ks], sf1, 0, 0, 0);
    }
    __builtin_amdgcn_s_setprio(0);

    float pm = fmaxf(rmax16(sf0), rmax16(sf1));   // already log2 units
    if (!__all(pm - mrun <= 8.0f)) {
      float mf = fmaxf(pm, __shfl_xor(pm, 32));
      float mn = fmaxf(mrun, mf);
      float corrl = exp2f(mrun - mn);
      mrun = mn;
      sBr[wave][l31] = corrl;
#pragma unroll
      for (int r = 0; r < 16; ++r) {
        float cr = sBr[wave][(r & 3) + 8 * (r >> 2) + 4 * hi];
        acc0[r] *= cr;
        acc1[r] *= cr;
        accL[r] *= cr;
      }
    }

    bf16x8 pa[4];
#pragma unroll
    for (int kb = 0; kb < 2; ++kb) {
      const f32x16 s16 = kb ? sf1 : sf0;
#pragma unroll
      for (int ksb = 0; ksb < 2; ++ksb) {
        float p0 = exp2f(s16[8 * ksb + 0] - mrun);
        float p1 = exp2f(s16[8 * ksb + 1] - mrun);
        float p2 = exp2f(s16[8 * ksb + 2] - mrun);
        float p3 = exp2f(s16[8 * ksb + 3] - mrun);
        float p4 = exp2f(s16[8 * ksb + 4] - mrun);
        float p5 = exp2f(s16[8 * ksb + 5] - mrun);
        float p6 = exp2f(s16[8 * ksb + 6] - mrun);
        float p7 = exp2f(s16[8 * ksb + 7] - mrun);
        unsigned wa = pkbf16(p0, p1), wb = pkbf16(p2, p3);
        unsigned wc = pkbf16(p4, p5), wd = pkbf16(p6, p7);
        auto r1 = __builtin_amdgcn_permlane32_swap(wa, wc, false, false);
        auto r2 = __builtin_amdgcn_permlane32_swap(wb, wd, false, false);
        union { unsigned u[4]; bf16x8 v; } w;
        w.u[0] = r1[0]; w.u[1] = r2[0]; w.u[2] = r1[1]; w.u[3] = r2[1];
        pa[kb * 2 + ksb] = w.v;
      }
    }

    __builtin_amdgcn_s_setprio(1);
#pragma unroll
    for (int ksg = 0; ksg < 4; ++ksg) {
      int colsw = (ksg * 16 + hi * 8) ^ rsw;
      bf16x8 vf0 = *(const bf16x8*)(&sV[cur][l31 * 64 + colsw]);
      bf16x8 vf1 = *(const bf16x8*)(&sV[cur][(32 + l31) * 64 + colsw]);
      acc0 = __builtin_amdgcn_mfma_f32_32x32x16_bf16(pa[ksg], vf0, acc0, 0, 0, 0);
      acc1 = __builtin_amdgcn_mfma_f32_32x32x16_bf16(pa[ksg], vf1, acc1, 0, 0, 0);
      accL = __builtin_amdgcn_mfma_f32_32x32x16_bf16(pa[ksg], onesb, accL, 0, 0, 0);
    }
    __builtin_amdgcn_s_setprio(0);
  }

#pragma unroll
  for (int r = 0; r < 16; ++r) {
    int qrow = (r & 3) + 8 * (r >> 2) + 4 * hi;
    float ir = 1.0f / accL[r];
    size_t obase = ((size_t)(b * S_ + q0 + wave * 32 + qrow)) * D_ + h * DH_ + l31;
    out[obase] = __float2bfloat16(acc0[r] * ir);
    out[obase + 32] = __float2bfloat16(acc1[r] * ir);
  }
}

// ====================================================================================
extern "C" void kernel_launch(void* const* d_in, const int* in_sizes, int n_in,
                              void* d_out, int out_size, void* d_ws, size_t ws_size,
                              hipStream_t stream) {
  const float* x = (const float*)d_in[0];
  const float* ln1_g = (const float*)d_in[1];
  const float* ln1_b = (const float*)d_in[2];
  const float* Wqkv = (const float*)d_in[3];
  const float* bqkv = (const float*)d_in[4];
  const float* Wo = (const float*)d_in[5];
  const float* bo = (const float*)d_in[6];
  const float* ln2_g = (const float*)d_in[7];
  const float* ln2_b = (const float*)d_in[8];
  const float* W1 = (const float*)d_in[9];
  const float* b1 = (const float*)d_in[10];
  const float* W2 = (const float*)d_in[11];
  const float* b2 = (const float*)d_in[12];
  float* out = (float*)d_out;

  char* ws = (char*)d_ws;
  size_t off = 0;
  auto alloc = [&](size_t bytes) {
    void* p = ws + off;
    off += (bytes + 255) & ~(size_t)255;
    return p;
  };
  __hip_bfloat16* WqkvT = (__hip_bfloat16*)alloc((size_t)3 * D_ * D_ * 2);
  __hip_bfloat16* WoT = (__hip_bfloat16*)alloc((size_t)D_ * D_ * 2);
  __hip_bfloat16* W1T = (__hip_bfloat16*)alloc((size_t)FF_ * D_ * 2);
  __hip_bfloat16* W2T = (__hip_bfloat16*)alloc((size_t)D_ * FF_ * 2);
  __hip_bfloat16* h = (__hip_bfloat16*)alloc((size_t)MR_ * D_ * 2);
  __hip_bfloat16* qkv = (__hip_bfloat16*)alloc((size_t)MR_ * FF_ * 2);  // shared w/ ff
  __hip_bfloat16* ff = qkv;
  __hip_bfloat16* vT = (__hip_bfloat16*)alloc((size_t)B_ * H_ * DH_ * S_ * 2);
  __hip_bfloat16* attn_out = (__hip_bfloat16*)alloc((size_t)MR_ * D_ * 2);

  dim3 tb(32, 8);
  // 1. weight prep
  transpose_cvt<<<dim3(3 * D_ / 32, D_ / 32), tb, 0, stream>>>(Wqkv, WqkvT, D_, 3 * D_);
  transpose_cvt<<<dim3(D_ / 32, D_ / 32), tb, 0, stream>>>(Wo, WoT, D_, D_);
  transpose_cvt<<<dim3(FF_ / 32, D_ / 32), tb, 0, stream>>>(W1, W1T, D_, FF_);
  transpose_cvt<<<dim3(D_ / 32, FF_ / 32), tb, 0, stream>>>(W2, W2T, FF_, D_);
  // 2. LN1
  ln_kernel<<<MR_, 256, 0, stream>>>(x, ln1_g, ln1_b, h);
  // 3. QKV gemm: grid (24,32) = 768, 2 blocks/CU resident
  gemm3<0><<<dim3(3 * D_ / 128, MR_ / 128), 512, 0, stream>>>(
      h, WqkvT, bqkv, nullptr, qkv, MR_, 3 * D_, D_);
  // 4. V transpose
  transpose_v<<<dim3(S_ / 32, DH_ / 32, B_ * H_), tb, 0, stream>>>(qkv, vT);
  // 5. attention (R9 config)
  attn_kernel<<<dim3(S_ / 128, B_ * H_), 256, 0, stream>>>(qkv, vT, attn_out);
  // 6. Wo gemm + residual -> d_out (fp32): grid (8,32) = 256
  gemm3<1><<<dim3(D_ / 128, MR_ / 128), 512, 0, stream>>>(
      attn_out, WoT, bo, x, out, MR_, D_, D_);
  // 7. LN2 (reuse h)
  ln_kernel<<<MR_, 256, 0, stream>>>(out, ln2_g, ln2_b, h);
  // 8. W1 gemm + gelu: grid (32,32) = 1024
  gemm3<2><<<dim3(FF_ / 128, MR_ / 128), 512, 0, stream>>>(
      h, W1T, b1, nullptr, ff, MR_, FF_, D_);
  // 9. W2 gemm + residual(d_out) -> d_out: grid (8,32) = 256
  gemm3<1><<<dim3(D_ / 128, MR_ / 128), 512, 0, stream>>>(
      ff, W2T, b2, out, out, MR_, D_, FF_);
}